// Round 1
// 1593.481 us; speedup vs baseline: 1.1965x; 1.1965x over previous
//
#include <hip/hip_runtime.h>
#include <hip/hip_bf16.h>
#include <cstdint>
#include <cstddef>

typedef __bf16 bf16_t;
typedef bf16_t bf16x8 __attribute__((ext_vector_type(8)));
typedef _Float16 f16_t;
typedef f16_t f16x8 __attribute__((ext_vector_type(8)));
typedef float f32x4 __attribute__((ext_vector_type(4)));

#define EPS_P 1e-4
#define RMS_EPS_D 1e-5
#define WSCALE 64.0f

// ---------- async global->LDS 16B (wave-uniform LDS base + lane*16) ----------
__device__ __forceinline__ void async_cp16(const void* g, void* l) {
  __builtin_amdgcn_global_load_lds(
      (const __attribute__((address_space(1))) unsigned int*)g,
      (__attribute__((address_space(3))) unsigned int*)l, 16, 0, 0);
}

#define SBAR() __builtin_amdgcn_s_barrier()
#define SCHED0() __builtin_amdgcn_sched_barrier(0)
#define LGKM0()                                        \
  do {                                                 \
    asm volatile("s_waitcnt lgkmcnt(0)" ::: "memory"); \
    __builtin_amdgcn_sched_barrier(0);                 \
  } while (0)
#define WAITV(N)                                           \
  do {                                                     \
    asm volatile("s_waitcnt vmcnt(" #N ")" ::: "memory");  \
    __builtin_amdgcn_sched_barrier(0);                     \
  } while (0)

// ---------------- transpose + cast fp32[R][C] -> bf16[C][R] ----------------
__global__ __launch_bounds__(256) void transpose_cast(
    const float* __restrict__ in, bf16_t* __restrict__ out, int R, int C) {
  __shared__ float tile[32][33];
  int c0 = blockIdx.x * 32, r0 = blockIdx.y * 32;
  int tx = threadIdx.x & 31, ty = threadIdx.x >> 5;  // 32x8
#pragma unroll
  for (int s = 0; s < 4; ++s) {
    int r = ty + s * 8;
    tile[r][tx] = in[(size_t)(r0 + r) * C + c0 + tx];
  }
  __syncthreads();
#pragma unroll
  for (int s = 0; s < 4; ++s) {
    int cc = ty + s * 8;
    out[(size_t)(c0 + cc) * R + r0 + tx] = (bf16_t)tile[tx][cc];
  }
}

// ------- transpose + scale + split fp32[R][C] -> fp16 hi/lo [C][R] -------
__global__ __launch_bounds__(256) void transpose_split(
    const float* __restrict__ in, f16_t* __restrict__ oh, f16_t* __restrict__ ol,
    int R, int C) {
  __shared__ float tile[32][33];
  int c0 = blockIdx.x * 32, r0 = blockIdx.y * 32;
  int tx = threadIdx.x & 31, ty = threadIdx.x >> 5;
#pragma unroll
  for (int s = 0; s < 4; ++s) {
    int r = ty + s * 8;
    tile[r][tx] = in[(size_t)(r0 + r) * C + c0 + tx];
  }
  __syncthreads();
#pragma unroll
  for (int s = 0; s < 4; ++s) {
    int cc = ty + s * 8;
    float v = tile[tx][cc] * WSCALE;
    f16_t hi = (f16_t)v;
    f16_t lo = (f16_t)(v - (float)hi);
    size_t idx = (size_t)(c0 + cc) * R + r0 + tx;
    oh[idx] = hi;
    ol[idx] = lo;
  }
}

// ---------------- elementwise split fp32 -> fp16 hi/lo ----------------
__global__ __launch_bounds__(256) void split_x(
    const float* __restrict__ x, f16_t* __restrict__ xh, f16_t* __restrict__ xl,
    int n4) {
  int i = blockIdx.x * 256 + threadIdx.x;
  if (i >= n4) return;
  float4 v = *(const float4*)(x + (size_t)i * 4);
  f16_t h0 = (f16_t)v.x, h1 = (f16_t)v.y, h2 = (f16_t)v.z, h3 = (f16_t)v.w;
  f16_t hv[4] = {h0, h1, h2, h3};
  f16_t lv[4] = {(f16_t)(v.x - (float)h0), (f16_t)(v.y - (float)h1),
                 (f16_t)(v.z - (float)h2), (f16_t)(v.w - (float)h3)};
  *(short4*)(xh + (size_t)i * 4) = *(short4*)hv;
  *(short4*)(xl + (size_t)i * 4) = *(short4*)lv;
}

// ---------------- RMSNorm (fp64 accum) + cast to bf16 ----------------
__global__ __launch_bounds__(256) void rmsnorm_cast(
    const float* __restrict__ X, const float* __restrict__ Wn,
    bf16_t* __restrict__ Xn, int d) {
  int row = blockIdx.x;
  const float* xr = X + (size_t)row * d;
  int t = threadIdx.x, l = t & 63, w = t >> 6;
  double ss = 0.0;
  for (int c = t * 4; c < d; c += 1024) {
    float4 v = *(const float4*)(xr + c);
    ss += (double)v.x * v.x + (double)v.y * v.y + (double)v.z * v.z + (double)v.w * v.w;
  }
#pragma unroll
  for (int o = 32; o > 0; o >>= 1) ss += __shfl_down(ss, o, 64);
  __shared__ double red[4];
  if (l == 0) red[w] = ss;
  __syncthreads();
  double tot = red[0] + red[1] + red[2] + red[3];
  float inv = (float)(1.0 / sqrt(tot / (double)d + RMS_EPS_D));
  for (int c = t * 4; c < d; c += 1024) {
    float4 v = *(const float4*)(xr + c);
    float4 wv = *(const float4*)(Wn + c);
    bf16_t* o = Xn + (size_t)row * d + c;
    o[0] = (bf16_t)(v.x * inv * wv.x);
    o[1] = (bf16_t)(v.y * inv * wv.y);
    o[2] = (bf16_t)(v.z * inv * wv.z);
    o[3] = (bf16_t)(v.w * inv * wv.w);
  }
}

// ------- fp16-split MFMA GEMM: Out[M,N] = (Ah+Al)[M,K] @ (Bh+Bl)[N,K]^T * outscale
// (drops Al*Bl term; single accumulator since all terms share exact scale) -------
__global__ __launch_bounds__(256) void gemm_f16_split(
    const f16_t* __restrict__ Ahg, const f16_t* __restrict__ Alg,
    const f16_t* __restrict__ Bhg, const f16_t* __restrict__ Blg,
    float* __restrict__ Out, int M, int N, int K, float outscale) {
  __shared__ f16_t Ah[128 * 32], Al[128 * 32], Bh[128 * 32], Bl[128 * 32];
  const int t = threadIdx.x, w = t >> 6, l = t & 63;
  const int m0 = blockIdx.y * 128, n0 = blockIdx.x * 128;
  const int wr = (w >> 1) * 64, wc = (w & 1) * 64;
  f32x4 acc[4][4] = {};
  const int ca0 = (w * 2) * 64 + l, ca1 = ca0 + 64;
  const int r0 = ca0 >> 2, ko0 = (ca0 & 3) * 8;
  const int r1 = ca1 >> 2, ko1 = (ca1 & 3) * 8;
  const int a_off = (wr + (l & 15)) * 32 + (l >> 4) * 8;
  const int b_off = (wc + (l & 15)) * 32 + (l >> 4) * 8;
  for (int k0 = 0; k0 < K; k0 += 32) {
    __syncthreads();
    async_cp16(Ahg + (size_t)(m0 + r0) * K + k0 + ko0, Ah + (w * 2 + 0) * 512);
    async_cp16(Ahg + (size_t)(m0 + r1) * K + k0 + ko1, Ah + (w * 2 + 1) * 512);
    async_cp16(Alg + (size_t)(m0 + r0) * K + k0 + ko0, Al + (w * 2 + 0) * 512);
    async_cp16(Alg + (size_t)(m0 + r1) * K + k0 + ko1, Al + (w * 2 + 1) * 512);
    async_cp16(Bhg + (size_t)(n0 + r0) * K + k0 + ko0, Bh + (w * 2 + 0) * 512);
    async_cp16(Bhg + (size_t)(n0 + r1) * K + k0 + ko1, Bh + (w * 2 + 1) * 512);
    async_cp16(Blg + (size_t)(n0 + r0) * K + k0 + ko0, Bl + (w * 2 + 0) * 512);
    async_cp16(Blg + (size_t)(n0 + r1) * K + k0 + ko1, Bl + (w * 2 + 1) * 512);
    __syncthreads();
    f16x8 ah[4], al[4], bh[4], bl[4];
#pragma unroll
    for (int i = 0; i < 4; ++i) {
      ah[i] = *(const f16x8*)(Ah + a_off + i * 512);
      al[i] = *(const f16x8*)(Al + a_off + i * 512);
    }
#pragma unroll
    for (int j = 0; j < 4; ++j) {
      bh[j] = *(const f16x8*)(Bh + b_off + j * 512);
      bl[j] = *(const f16x8*)(Bl + b_off + j * 512);
    }
#pragma unroll
    for (int i = 0; i < 4; ++i)
#pragma unroll
      for (int j = 0; j < 4; ++j) {
        acc[i][j] = __builtin_amdgcn_mfma_f32_16x16x32_f16(ah[i], bh[j], acc[i][j], 0, 0, 0);
        acc[i][j] = __builtin_amdgcn_mfma_f32_16x16x32_f16(ah[i], bl[j], acc[i][j], 0, 0, 0);
        acc[i][j] = __builtin_amdgcn_mfma_f32_16x16x32_f16(al[i], bh[j], acc[i][j], 0, 0, 0);
      }
  }
  const int col_l = l & 15, row_q = (l >> 4) * 4;
#pragma unroll
  for (int i = 0; i < 4; ++i)
#pragma unroll
    for (int j = 0; j < 4; ++j) {
      int col = n0 + wc + j * 16 + col_l;
#pragma unroll
      for (int r = 0; r < 4; ++r) {
        int row = m0 + wr + i * 16 + row_q + r;
        Out[(size_t)row * N + col] = acc[i][j][r] * outscale;
      }
    }
}

// ---------------- cos / p / a / b per token (fp64 accum dots) ----------------
// QK layout: [T, 4096], q_t = QK[t, 0:2048], k_t = QK[t, 2048:4096]
__global__ __launch_bounds__(256) void cos_p(
    const float* __restrict__ QK,
    const int* __restrict__ cu, int ncu,
    float* __restrict__ P, float* __restrict__ Aarr, float* __restrict__ Bf,
    int d) {
  int tk = blockIdx.x;
  int t = threadIdx.x, l = t & 63, w = t >> 6;
  __shared__ double rqk[4], rqq[4], rkk[4];
  double s_qk = 0, s_qq = 0, s_kk = 0;
  if (tk > 0) {
    const float* qr = QK + (size_t)(tk - 1) * (2 * d);
    const float* kr = QK + (size_t)tk * (2 * d) + d;
    for (int c = t * 4; c < d; c += 1024) {
      float4 qv = *(const float4*)(qr + c);
      float4 kv = *(const float4*)(kr + c);
      s_qk += (double)qv.x * kv.x + (double)qv.y * kv.y + (double)qv.z * kv.z + (double)qv.w * kv.w;
      s_qq += (double)qv.x * qv.x + (double)qv.y * qv.y + (double)qv.z * qv.z + (double)qv.w * qv.w;
      s_kk += (double)kv.x * kv.x + (double)kv.y * kv.y + (double)kv.z * kv.z + (double)kv.w * kv.w;
    }
#pragma unroll
    for (int o = 32; o > 0; o >>= 1) {
      s_qk += __shfl_down(s_qk, o, 64);
      s_qq += __shfl_down(s_qq, o, 64);
      s_kk += __shfl_down(s_kk, o, 64);
    }
    if (l == 0) { rqk[w] = s_qk; rqq[w] = s_qq; rkk[w] = s_kk; }
    __syncthreads();
  }
  if (t == 0) {
    bool start = false;
    for (int i = 0; i + 1 < ncu; ++i)
      if (cu[i] == tk) start = true;
    double p;
    if (tk == 0) {
      p = 1.0;
    } else {
      double dqk = rqk[0] + rqk[1] + rqk[2] + rqk[3];
      double dqq = rqq[0] + rqq[1] + rqq[2] + rqq[3];
      double dkk = rkk[0] + rkk[1] + rkk[2] + rkk[3];
      double cosv = dqk / sqrt(dqq * dkk);
      p = (1.0 - cosv) * 0.5;
    }
    if (start) p = 1.0;
    if (p < EPS_P) p = EPS_P;
    if (p > 1.0 - EPS_P) p = 1.0 - EPS_P;
    float b = (p >= 0.5) ? 1.0f : 0.0f;
    float a = start ? 0.0f : ((b > 0.5f) ? (float)(1.0 - p) : 1.0f);
    P[tk] = (float)p; Aarr[tk] = a; Bf[tk] = b;
  }
}

// ---------------- intra-chunk prefix products of a (chunk = 64) ----------------
__global__ void pfx_kernel(const float* __restrict__ Aarr, float* __restrict__ Pfx,
                           float* __restrict__ Ac, int T) {
  int c = threadIdx.x;
  if (c * 64 < T) {
    float Pv = 1.0f;
    for (int i = 0; i < 64; ++i) {
      int tt = c * 64 + i;
      Pv *= Aarr[tt];
      Pfx[tt] = Pv;
    }
    Ac[c] = Pv;
  }
}

// ================= 256x256 8-phase bf16 GEMM (T2+T3+T4+T5) =================
// Computes C[256 rows x 256 B-rows] per block; 8 waves as 4M x 2N; per-wave
// 64 rows x 128 cols as acc[2][4][4] (p = B-half).
//   SWIGLU=false: Outf[row*N+col] = X[idx] + acc   (B-halves = cols n0..n0+255)
//   SWIGLU=true : Outb[row*N+col] = silu(acc[1]) * acc[0]
//                 (B-half0 = fc1t rows n0.., B-half1 = fc1t rows H+n0..)
// LDS: 2 buffers x {A,B} x 256 rows x 64 k (128 B/row), 16B-granule XOR
// swizzle gran^=(row&7); staged via global_load_lds with inverse-swizzled
// global source (linear LDS dest). Counted-vmcnt pipeline, raw s_barrier.
template <bool SWIGLU>
__global__ __launch_bounds__(512, 2) void gemm256(
    const bf16_t* __restrict__ A, const bf16_t* __restrict__ B,
    const float* __restrict__ X, float* __restrict__ Outf,
    bf16_t* __restrict__ Outb, int M, int N, int K, int H) {
  __shared__ char lds[2][2][32768];  // [buf][A=0/B=1][256 rows * 128 B]
  const int t = threadIdx.x;
  const int l = t & 63, w = t >> 6;
  const int wm = w >> 1, wn = w & 1;  // 4M x 2N wave grid
  const int m0 = blockIdx.y * 256;
  const int NT = K >> 6;  // K-tiles of 64 (assumes NT >= 2)
  const size_t sB = (size_t)K * 2;  // global row stride, bytes
  const int nb = blockIdx.x * (SWIGLU ? 128 : 256);
  const char* Ab = (const char*)A + (size_t)m0 * sB;
  const char* Bb0 = (const char*)B + (size_t)nb * sB;
  const char* Bb1 = (const char*)B + (size_t)(SWIGLU ? (H + nb) : (nb + 128)) * sB;
  // staging lane constants: lane covers (row = chunk*8 + l>>3, logical gran
  // cg = (l&7) ^ (l>>3)) so that linear LDS slot holds swizzled layout
  const int srow = l >> 3;
  const size_t laneoff = (size_t)srow * sB + (size_t)(((l & 7) ^ srow) << 4);
  // frag-read lane constants (byte offsets inside a row block)
  const int fr_row = (l & 15) << 7;                      // (l&15)*128
  const int g0 = (((l >> 4) ^ (l & 7)) << 4);            // k-sub 0 granule
  const int g1 = ((((l >> 4) + 4) ^ (l & 7)) << 4);      // k-sub 1 granule
  f32x4 acc[2][4][4] = {};

  auto STAGE = [&](const char* src, char* ldsb) {
    // wave w loads chunks 2w, 2w+1 of a 128x64 half-tile (1 KB each)
    const char* s = src + (size_t)(w << 4) * sB + laneoff;
    async_cp16(s, ldsb + (w << 11));
    async_cp16(s + 8 * sB, ldsb + (w << 11) + 1024);
  };

  // prologue: A0(0) A1(0) B0(0) B1(0) A0(1) A1(1) B0(1)  [14 loads/wave]
  STAGE(Ab, lds[0][0]);
  STAGE(Ab + 128 * sB, lds[0][0] + 16384);
  STAGE(Bb0, lds[0][1]);
  STAGE(Bb1, lds[0][1] + 16384);
  STAGE(Ab + 128, lds[1][0]);
  STAGE(Ab + 128 * sB + 128, lds[1][0] + 16384);
  STAGE(Bb0 + 128, lds[1][1]);
  WAITV(6);  // buf0 fully resident; {A0,A1,B0}(1) still in flight
  SBAR();

  for (int kt = 0; kt < NT; ++kt) {
    const int buf = kt & 1;
    char* Als = lds[buf][0];
    char* Bls = lds[buf][1];
    const char* Abl = Als + ((wm << 6) << 7) + fr_row;  // + wm*64 rows
    const char* Bbl = Bls + ((wn << 6) << 7) + fr_row;  // + wn*64 rows
    bf16x8 a0[4], a1[4], bfr[4];

    // ---- phase 1: (p=0, ks=0); reads all A frags + B(p0,k0); stage B1(kt+1)
#pragma unroll
    for (int i = 0; i < 4; ++i) {
      a0[i] = *(const bf16x8*)(Abl + i * 2048 + g0);
      a1[i] = *(const bf16x8*)(Abl + i * 2048 + g1);
    }
#pragma unroll
    for (int j = 0; j < 4; ++j) bfr[j] = *(const bf16x8*)(Bbl + j * 2048 + g0);
    if (kt + 1 < NT) STAGE(Bb1 + (size_t)(kt + 1) * 128, lds[buf ^ 1][1] + 16384);
    SBAR();
    LGKM0();
    __builtin_amdgcn_s_setprio(1);
#pragma unroll
    for (int i = 0; i < 4; ++i)
#pragma unroll
      for (int j = 0; j < 4; ++j)
        acc[0][i][j] = __builtin_amdgcn_mfma_f32_16x16x32_bf16(a0[i], bfr[j], acc[0][i][j], 0, 0, 0);
    __builtin_amdgcn_s_setprio(0);
    SCHED0();
    SBAR();

    // ---- phase 2: (p=0, ks=1); stage A0(kt+2)
#pragma unroll
    for (int j = 0; j < 4; ++j) bfr[j] = *(const bf16x8*)(Bbl + j * 2048 + g1);
    if (kt + 2 < NT) STAGE(Ab + (size_t)(kt + 2) * 128, Als);
    SBAR();
    LGKM0();
    __builtin_amdgcn_s_setprio(1);
#pragma unroll
    for (int i = 0; i < 4; ++i)
#pragma unroll
      for (int j = 0; j < 4; ++j)
        acc[0][i][j] = __builtin_amdgcn_mfma_f32_16x16x32_bf16(a1[i], bfr[j], acc[0][i][j], 0, 0, 0);
    __builtin_amdgcn_s_setprio(0);
    SCHED0();
    SBAR();

    // ---- phase 3: (p=1, ks=0); stage A1(kt+2), B0(kt+2)
#pragma unroll
    for (int j = 0; j < 4; ++j) bfr[j] = *(const bf16x8*)(Bbl + 16384 + j * 2048 + g0);
    if (kt + 2 < NT) {
      STAGE(Ab + 128 * sB + (size_t)(kt + 2) * 128, Als + 16384);
      STAGE(Bb0 + (size_t)(kt + 2) * 128, Bls);
    }
    SBAR();
    LGKM0();
    __builtin_amdgcn_s_setprio(1);
#pragma unroll
    for (int i = 0; i < 4; ++i)
#pragma unroll
      for (int j = 0; j < 4; ++j)
        acc[1][i][j] = __builtin_amdgcn_mfma_f32_16x16x32_bf16(a0[i], bfr[j], acc[1][i][j], 0, 0, 0);
    __builtin_amdgcn_s_setprio(0);
    SCHED0();
    SBAR();

    // ---- phase 4: (p=1, ks=1); counted vmcnt, then buffer switch
#pragma unroll
    for (int j = 0; j < 4; ++j) bfr[j] = *(const bf16x8*)(Bbl + 16384 + j * 2048 + g1);
    SBAR();
    LGKM0();
    __builtin_amdgcn_s_setprio(1);
#pragma unroll
    for (int i = 0; i < 4; ++i)
#pragma unroll
      for (int j = 0; j < 4; ++j)
        acc[1][i][j] = __builtin_amdgcn_mfma_f32_16x16x32_bf16(a1[i], bfr[j], acc[1][i][j], 0, 0, 0);
    __builtin_amdgcn_s_setprio(0);
    SCHED0();
    if (kt + 1 < NT) {
      if (kt + 2 < NT) WAITV(6);  // leaves {A0,A1,B0}(kt+2) in flight
      else WAITV(0);
    }
    SBAR();
  }

  // ---- epilogue ----
  const int col_l = l & 15, row_q = (l >> 4) * 4;
  if (SWIGLU) {
    const int ucol0 = nb + (wn << 6);
#pragma unroll
    for (int i = 0; i < 4; ++i)
#pragma unroll
      for (int j = 0; j < 4; ++j) {
        const int col = ucol0 + j * 16 + col_l;
        const int row = m0 + (wm << 6) + i * 16 + row_q;
#pragma unroll
        for (int r = 0; r < 4; ++r) {
          float hh = acc[0][i][j][r];
          float g = acc[1][i][j][r];
          float s = g / (1.0f + expf(-g));
          Outb[(size_t)(row + r) * N + col] = (bf16_t)(s * hh);
        }
      }
  } else {
#pragma unroll
    for (int p = 0; p < 2; ++p)
#pragma unroll
      for (int i = 0; i < 4; ++i)
#pragma unroll
        for (int j = 0; j < 4; ++j) {
          const int col = nb + p * 128 + (wn << 6) + j * 16 + col_l;
          const int row = m0 + (wm << 6) + i * 16 + row_q;
#pragma unroll
          for (int r = 0; r < 4; ++r) {
            size_t idx = (size_t)(row + r) * N + col;
            Outf[idx] = X[idx] + acc[p][i][j][r];
          }
        }
  }
}

// ---------------- scan pass 1: per-chunk local scan, in-place on Z (d_out) ----------------
__global__ __launch_bounds__(256) void scan1(
    float* __restrict__ Z, const float* __restrict__ P,
    const float* __restrict__ Aarr, const float* __restrict__ Bf, int d) {
  int c = blockIdx.x;
  int col = blockIdx.y * 512 + threadIdx.x * 2;
  __shared__ float sa[64], sp[64], sb[64];
  if (threadIdx.x < 64) {
    int tt = c * 64 + threadIdx.x;
    sa[threadIdx.x] = Aarr[tt];
    sp[threadIdx.x] = P[tt];
    sb[threadIdx.x] = Bf[tt];
  }
  __syncthreads();
  float hx = 0.0f, hy = 0.0f;
  for (int i = 0; i < 64; ++i) {
    int row = c * 64 + i;
    float a = sa[i];
    float2* zp = (float2*)(Z + (size_t)row * d + col);
    if (sb[i] > 0.5f) {
      float2 zv = *zp;
      float pp = sp[i];
      hx = a * hx + pp * zv.x;
      hy = a * hy + pp * zv.y;
    } else {
      hx = a * hx;
      hy = a * hy;
    }
    float2 hv; hv.x = hx; hv.y = hy;
    *zp = hv;
  }
}

// ---------------- scan pass 2: chunk-level carry scan ----------------
__global__ __launch_bounds__(256) void scan2(
    const float* __restrict__ Z, const float* __restrict__ Ac,
    float* __restrict__ Hprev, int d, int NC) {
  int col = blockIdx.x * 256 + threadIdx.x;
  float H = 0.0f;
  for (int c = 0; c < NC; ++c) {
    Hprev[(size_t)c * d + col] = H;
    float E = Z[(size_t)(c * 64 + 63) * d + col];
    H = Ac[c] * H + E;
  }
}

// ---------------- scan pass 3: add carry * intra-chunk prefix ----------------
__global__ __launch_bounds__(256) void scan3(
    float* __restrict__ Z, const float* __restrict__ Pfx,
    const float* __restrict__ Hprev, int d) {
  int row = blockIdx.x;
  int c = row >> 6;
  float pf = Pfx[row];
  int col = threadIdx.x * 8;
  const float* hp = Hprev + (size_t)c * d + col;
  float4 h0 = *(const float4*)hp;
  float4 h1 = *(const float4*)(hp + 4);
  float* zp = Z + (size_t)row * d + col;
  float4 z0 = *(const float4*)zp;
  float4 z1 = *(const float4*)(zp + 4);
  z0.x += pf * h0.x; z0.y += pf * h0.y; z0.z += pf * h0.z; z0.w += pf * h0.w;
  z1.x += pf * h1.x; z1.y += pf * h1.y; z1.z += pf * h1.z; z1.w += pf * h1.w;
  *(float4*)zp = z0;
  *(float4*)(zp + 4) = z1;
}

// ---------------- host ----------------
extern "C" void kernel_launch(void* const* d_in, const int* in_sizes, int n_in,
                              void* d_out, int out_size, void* d_ws, size_t ws_size,
                              hipStream_t stream) {
  const float* x   = (const float*)d_in[0];
  const float* Wq  = (const float*)d_in[1];
  const float* Wk  = (const float*)d_in[2];
  const float* fc1 = (const float*)d_in[3];
  const float* fc2 = (const float*)d_in[4];
  const float* nw  = (const float*)d_in[5];
  const int*   cu  = (const int*)d_in[6];
  const int ncu = in_sizes[6];
  const int d = in_sizes[5];            // 2048
  const int T = in_sizes[0] / d;        // 8192
  const int h = in_sizes[4] / d;        // 8192
  const int NC = T / 64;                // 128 chunks
  float* zout = (float*)d_out;

  char* ws = (char*)d_ws;
  size_t off = 0;
  auto alloc = [&](size_t bytes) -> void* {
    void* p = ws + off;
    off += (bytes + 255) & ~(size_t)255;
    return p;
  };
  // qk [T, 2d] fp32; later reused as u [T, h] bf16 (same byte size)
  float*  qk   = (float*)alloc((size_t)T * 2 * d * 4);
  bf16_t* u    = (bf16_t*)qk;
  bf16_t* xn   = (bf16_t*)alloc((size_t)T * d * 2);
  // region A: first {Xh, Xl, Wth, Wtl} (fp16 splits), later {fc1t, fc2t} (bf16)
  size_t szXh = (size_t)T * d * 2;          // 33.5 MB
  size_t szWt = (size_t)2 * d * d * 2;      // 16.8 MB
  char* regionA = (char*)alloc(2 * szXh + 2 * szWt);
  f16_t* Xh  = (f16_t*)regionA;
  f16_t* Xl  = (f16_t*)(regionA + szXh);
  f16_t* Wth = (f16_t*)(regionA + 2 * szXh);
  f16_t* Wtl = (f16_t*)(regionA + 2 * szXh + szWt);
  bf16_t* fc1t = (bf16_t*)regionA;                           // [2h, d]
  bf16_t* fc2t = (bf16_t*)(regionA + (size_t)2 * h * d * 2); // [d, h]
  float*  P    = (float*)alloc((size_t)T * 4);
  float*  Aa   = (float*)alloc((size_t)T * 4);
  float*  Bf   = (float*)alloc((size_t)T * 4);
  float*  Pfx  = (float*)alloc((size_t)T * 4);
  float*  Ac   = (float*)alloc((size_t)NC * 4);
  float*  Hprev= (float*)alloc((size_t)NC * d * 4);

  // ---- routing: q/k projections on matrix cores via fp16 split ----
  split_x<<<dim3(T * d / 1024), 256, 0, stream>>>(x, Xh, Xl, T * d / 4);
  transpose_split<<<dim3(d / 32, d / 32), 256, 0, stream>>>(Wq, Wth, Wtl, d, d);
  transpose_split<<<dim3(d / 32, d / 32), 256, 0, stream>>>(
      Wk, Wth + (size_t)d * d, Wtl + (size_t)d * d, d, d);
  gemm_f16_split<<<dim3(2 * d / 128, T / 128), 256, 0, stream>>>(
      Xh, Xl, Wth, Wtl, qk, T, 2 * d, d, 1.0f / WSCALE);
  cos_p<<<dim3(T), 256, 0, stream>>>(qk, cu, ncu, P, Aa, Bf, d);
  pfx_kernel<<<dim3(1), 128, 0, stream>>>(Aa, Pfx, Ac, T);

  // ---- MLP weights into region A (splits dead now) ----
  transpose_cast<<<dim3(2 * h / 32, d / 32), 256, 0, stream>>>(fc1, fc1t, d, 2 * h);
  transpose_cast<<<dim3(d / 32, h / 32), 256, 0, stream>>>(fc2, fc2t, h, d);
  rmsnorm_cast<<<dim3(T), 256, 0, stream>>>(x, nw, xn, d);
  // u reuses qk space (qk dead after cos_p)
  gemm256<true><<<dim3(h / 128, T / 256), 512, 0, stream>>>(
      xn, fc1t, nullptr, nullptr, u, T, h, d, h);
  gemm256<false><<<dim3(d / 256, T / 256), 512, 0, stream>>>(
      u, fc2t, x, zout, nullptr, T, d, h, 0);
  // ---- EMA scan (3 passes, in place on d_out) ----
  scan1<<<dim3(NC, d / 512), 256, 0, stream>>>(zout, P, Aa, Bf, d);
  scan2<<<dim3(d / 256), 256, 0, stream>>>(zout, Ac, Hprev, d, NC);
  scan3<<<dim3(T), 256, 0, stream>>>(zout, Pfx, Hprev, d);
}

// Round 3
// 1512.020 us; speedup vs baseline: 1.2610x; 1.0539x over previous
//
#include <hip/hip_runtime.h>
#include <hip/hip_bf16.h>
#include <cstdint>
#include <cstddef>

typedef __bf16 bf16_t;
typedef bf16_t bf16x8 __attribute__((ext_vector_type(8)));
typedef _Float16 f16_t;
typedef f16_t f16x8 __attribute__((ext_vector_type(8)));
typedef float f32x4 __attribute__((ext_vector_type(4)));

#define EPS_P 1e-4
#define RMS_EPS_D 1e-5
#define WSCALE 64.0f

// ---------- async global->LDS 16B (wave-uniform LDS base + lane*16) ----------
__device__ __forceinline__ void async_cp16(const void* g, void* l) {
  __builtin_amdgcn_global_load_lds(
      (const __attribute__((address_space(1))) unsigned int*)g,
      (__attribute__((address_space(3))) unsigned int*)l, 16, 0, 0);
}

#define SBAR() __builtin_amdgcn_s_barrier()
#define SCHED0() __builtin_amdgcn_sched_barrier(0)
#define WAITV(N)                                           \
  do {                                                     \
    asm volatile("s_waitcnt vmcnt(" #N ")" ::: "memory");  \
    __builtin_amdgcn_sched_barrier(0);                     \
  } while (0)

// ---------------- transpose + cast fp32[R][C] -> bf16[C][R] ----------------
__global__ __launch_bounds__(256) void transpose_cast(
    const float* __restrict__ in, bf16_t* __restrict__ out, int R, int C) {
  __shared__ float tile[32][33];
  int c0 = blockIdx.x * 32, r0 = blockIdx.y * 32;
  int tx = threadIdx.x & 31, ty = threadIdx.x >> 5;  // 32x8
#pragma unroll
  for (int s = 0; s < 4; ++s) {
    int r = ty + s * 8;
    tile[r][tx] = in[(size_t)(r0 + r) * C + c0 + tx];
  }
  __syncthreads();
#pragma unroll
  for (int s = 0; s < 4; ++s) {
    int cc = ty + s * 8;
    out[(size_t)(c0 + cc) * R + r0 + tx] = (bf16_t)tile[tx][cc];
  }
}

// ------- transpose + scale + split fp32[R][C] -> fp16 hi/lo [C][R] -------
__global__ __launch_bounds__(256) void transpose_split(
    const float* __restrict__ in, f16_t* __restrict__ oh, f16_t* __restrict__ ol,
    int R, int C) {
  __shared__ float tile[32][33];
  int c0 = blockIdx.x * 32, r0 = blockIdx.y * 32;
  int tx = threadIdx.x & 31, ty = threadIdx.x >> 5;
#pragma unroll
  for (int s = 0; s < 4; ++s) {
    int r = ty + s * 8;
    tile[r][tx] = in[(size_t)(r0 + r) * C + c0 + tx];
  }
  __syncthreads();
#pragma unroll
  for (int s = 0; s < 4; ++s) {
    int cc = ty + s * 8;
    float v = tile[tx][cc] * WSCALE;
    f16_t hi = (f16_t)v;
    f16_t lo = (f16_t)(v - (float)hi);
    size_t idx = (size_t)(c0 + cc) * R + r0 + tx;
    oh[idx] = hi;
    ol[idx] = lo;
  }
}

// ---------------- elementwise split fp32 -> fp16 hi/lo ----------------
__global__ __launch_bounds__(256) void split_x(
    const float* __restrict__ x, f16_t* __restrict__ xh, f16_t* __restrict__ xl,
    int n4) {
  int i = blockIdx.x * 256 + threadIdx.x;
  if (i >= n4) return;
  float4 v = *(const float4*)(x + (size_t)i * 4);
  f16_t h0 = (f16_t)v.x, h1 = (f16_t)v.y, h2 = (f16_t)v.z, h3 = (f16_t)v.w;
  f16_t hv[4] = {h0, h1, h2, h3};
  f16_t lv[4] = {(f16_t)(v.x - (float)h0), (f16_t)(v.y - (float)h1),
                 (f16_t)(v.z - (float)h2), (f16_t)(v.w - (float)h3)};
  *(short4*)(xh + (size_t)i * 4) = *(short4*)hv;
  *(short4*)(xl + (size_t)i * 4) = *(short4*)lv;
}

// ---------------- RMSNorm (fp64 accum) + cast to bf16 ----------------
__global__ __launch_bounds__(256) void rmsnorm_cast(
    const float* __restrict__ X, const float* __restrict__ Wn,
    bf16_t* __restrict__ Xn, int d) {
  int row = blockIdx.x;
  const float* xr = X + (size_t)row * d;
  int t = threadIdx.x, l = t & 63, w = t >> 6;
  double ss = 0.0;
  for (int c = t * 4; c < d; c += 1024) {
    float4 v = *(const float4*)(xr + c);
    ss += (double)v.x * v.x + (double)v.y * v.y + (double)v.z * v.z + (double)v.w * v.w;
  }
#pragma unroll
  for (int o = 32; o > 0; o >>= 1) ss += __shfl_down(ss, o, 64);
  __shared__ double red[4];
  if (l == 0) red[w] = ss;
  __syncthreads();
  double tot = red[0] + red[1] + red[2] + red[3];
  float inv = (float)(1.0 / sqrt(tot / (double)d + RMS_EPS_D));
  for (int c = t * 4; c < d; c += 1024) {
    float4 v = *(const float4*)(xr + c);
    float4 wv = *(const float4*)(Wn + c);
    bf16_t* o = Xn + (size_t)row * d + c;
    o[0] = (bf16_t)(v.x * inv * wv.x);
    o[1] = (bf16_t)(v.y * inv * wv.y);
    o[2] = (bf16_t)(v.z * inv * wv.z);
    o[3] = (bf16_t)(v.w * inv * wv.w);
  }
}

// ------- fp16-split MFMA GEMM: Out[M,N] = (Ah+Al)[M,K] @ (Bh+Bl)[N,K]^T * outscale
// (drops Al*Bl term; single accumulator since all terms share exact scale) -------
__global__ __launch_bounds__(256) void gemm_f16_split(
    const f16_t* __restrict__ Ahg, const f16_t* __restrict__ Alg,
    const f16_t* __restrict__ Bhg, const f16_t* __restrict__ Blg,
    float* __restrict__ Out, int M, int N, int K, float outscale) {
  __shared__ f16_t Ah[128 * 32], Al[128 * 32], Bh[128 * 32], Bl[128 * 32];
  const int t = threadIdx.x, w = t >> 6, l = t & 63;
  const int m0 = blockIdx.y * 128, n0 = blockIdx.x * 128;
  const int wr = (w >> 1) * 64, wc = (w & 1) * 64;
  f32x4 acc[4][4] = {};
  const int ca0 = (w * 2) * 64 + l, ca1 = ca0 + 64;
  const int r0 = ca0 >> 2, ko0 = (ca0 & 3) * 8;
  const int r1 = ca1 >> 2, ko1 = (ca1 & 3) * 8;
  const int a_off = (wr + (l & 15)) * 32 + (l >> 4) * 8;
  const int b_off = (wc + (l & 15)) * 32 + (l >> 4) * 8;
  for (int k0 = 0; k0 < K; k0 += 32) {
    __syncthreads();
    async_cp16(Ahg + (size_t)(m0 + r0) * K + k0 + ko0, Ah + (w * 2 + 0) * 512);
    async_cp16(Ahg + (size_t)(m0 + r1) * K + k0 + ko1, Ah + (w * 2 + 1) * 512);
    async_cp16(Alg + (size_t)(m0 + r0) * K + k0 + ko0, Al + (w * 2 + 0) * 512);
    async_cp16(Alg + (size_t)(m0 + r1) * K + k0 + ko1, Al + (w * 2 + 1) * 512);
    async_cp16(Bhg + (size_t)(n0 + r0) * K + k0 + ko0, Bh + (w * 2 + 0) * 512);
    async_cp16(Bhg + (size_t)(n0 + r1) * K + k0 + ko1, Bh + (w * 2 + 1) * 512);
    async_cp16(Blg + (size_t)(n0 + r0) * K + k0 + ko0, Bl + (w * 2 + 0) * 512);
    async_cp16(Blg + (size_t)(n0 + r1) * K + k0 + ko1, Bl + (w * 2 + 1) * 512);
    __syncthreads();
    f16x8 ah[4], al[4], bh[4], bl[4];
#pragma unroll
    for (int i = 0; i < 4; ++i) {
      ah[i] = *(const f16x8*)(Ah + a_off + i * 512);
      al[i] = *(const f16x8*)(Al + a_off + i * 512);
    }
#pragma unroll
    for (int j = 0; j < 4; ++j) {
      bh[j] = *(const f16x8*)(Bh + b_off + j * 512);
      bl[j] = *(const f16x8*)(Bl + b_off + j * 512);
    }
#pragma unroll
    for (int i = 0; i < 4; ++i)
#pragma unroll
      for (int j = 0; j < 4; ++j) {
        acc[i][j] = __builtin_amdgcn_mfma_f32_16x16x32_f16(ah[i], bh[j], acc[i][j], 0, 0, 0);
        acc[i][j] = __builtin_amdgcn_mfma_f32_16x16x32_f16(ah[i], bl[j], acc[i][j], 0, 0, 0);
        acc[i][j] = __builtin_amdgcn_mfma_f32_16x16x32_f16(al[i], bh[j], acc[i][j], 0, 0, 0);
      }
  }
  const int col_l = l & 15, row_q = (l >> 4) * 4;
#pragma unroll
  for (int i = 0; i < 4; ++i)
#pragma unroll
    for (int j = 0; j < 4; ++j) {
      int col = n0 + wc + j * 16 + col_l;
#pragma unroll
      for (int r = 0; r < 4; ++r) {
        int row = m0 + wr + i * 16 + row_q + r;
        Out[(size_t)row * N + col] = acc[i][j][r] * outscale;
      }
    }
}

// ---------------- cos / p / a / b per token (fp64 accum dots) ----------------
// QK layout: [T, 4096], q_t = QK[t, 0:2048], k_t = QK[t, 2048:4096]
__global__ __launch_bounds__(256) void cos_p(
    const float* __restrict__ QK,
    const int* __restrict__ cu, int ncu,
    float* __restrict__ P, float* __restrict__ Aarr, float* __restrict__ Bf,
    int d) {
  int tk = blockIdx.x;
  int t = threadIdx.x, l = t & 63, w = t >> 6;
  __shared__ double rqk[4], rqq[4], rkk[4];
  double s_qk = 0, s_qq = 0, s_kk = 0;
  if (tk > 0) {
    const float* qr = QK + (size_t)(tk - 1) * (2 * d);
    const float* kr = QK + (size_t)tk * (2 * d) + d;
    for (int c = t * 4; c < d; c += 1024) {
      float4 qv = *(const float4*)(qr + c);
      float4 kv = *(const float4*)(kr + c);
      s_qk += (double)qv.x * kv.x + (double)qv.y * kv.y + (double)qv.z * kv.z + (double)qv.w * kv.w;
      s_qq += (double)qv.x * qv.x + (double)qv.y * qv.y + (double)qv.z * qv.z + (double)qv.w * qv.w;
      s_kk += (double)kv.x * kv.x + (double)kv.y * kv.y + (double)kv.z * kv.z + (double)kv.w * kv.w;
    }
#pragma unroll
    for (int o = 32; o > 0; o >>= 1) {
      s_qk += __shfl_down(s_qk, o, 64);
      s_qq += __shfl_down(s_qq, o, 64);
      s_kk += __shfl_down(s_kk, o, 64);
    }
    if (l == 0) { rqk[w] = s_qk; rqq[w] = s_qq; rkk[w] = s_kk; }
    __syncthreads();
  }
  if (t == 0) {
    bool start = false;
    for (int i = 0; i + 1 < ncu; ++i)
      if (cu[i] == tk) start = true;
    double p;
    if (tk == 0) {
      p = 1.0;
    } else {
      double dqk = rqk[0] + rqk[1] + rqk[2] + rqk[3];
      double dqq = rqq[0] + rqq[1] + rqq[2] + rqq[3];
      double dkk = rkk[0] + rkk[1] + rkk[2] + rkk[3];
      double cosv = dqk / sqrt(dqq * dkk);
      p = (1.0 - cosv) * 0.5;
    }
    if (start) p = 1.0;
    if (p < EPS_P) p = EPS_P;
    if (p > 1.0 - EPS_P) p = 1.0 - EPS_P;
    float b = (p >= 0.5) ? 1.0f : 0.0f;
    float a = start ? 0.0f : ((b > 0.5f) ? (float)(1.0 - p) : 1.0f);
    P[tk] = (float)p; Aarr[tk] = a; Bf[tk] = b;
  }
}

// ---------------- intra-chunk prefix products of a (chunk = 64) ----------------
__global__ void pfx_kernel(const float* __restrict__ Aarr, float* __restrict__ Pfx,
                           float* __restrict__ Ac, int T) {
  int c = threadIdx.x;
  if (c * 64 < T) {
    float Pv = 1.0f;
    for (int i = 0; i < 64; ++i) {
      int tt = c * 64 + i;
      Pv *= Aarr[tt];
      Pfx[tt] = Pv;
    }
    Ac[c] = Pv;
  }
}

// ================= 256x256 4-phase pipelined bf16 GEMM =================
// T2 (LDS XOR swizzle) + T3/T4 (counted vmcnt) + T5 (setprio) + fragment-read
// software pipeline (each phase issues ds_reads for the NEXT phase's MFMA; no
// explicit lgkm drain — compiler emits counted lgkmcnt for consumed operands).
// CROSS-WAVE SAFETY INVARIANT (round-2 post-mortem): a wave must vmcnt-wait
// for its own staging of region R BEFORE the barrier that precedes any wave's
// read of R. Hence waits sit at END of ph1 / ph3 (pre-barrier), not at the
// start of the reading phase.
// Per K-tile kt (buf b = kt&1):
//   ph1: rd {a1(b,g1), bY=B(b,p0,g1)}  st B1(kt+1)  MFMA a0*bX->acc0
//        WAITV(8) [lands B1(kt) for ph2]  SBAR
//   ph2: rd {bX=B(b,p1,g0)}                         MFMA a1*bY->acc0  SBAR
//   ph3: rd {bY=B(b,p1,g1)}            st A0(kt+2)  MFMA a0*bX->acc1
//        WAITV(4) [lands {A0,A1,B0}(kt+1) for ph4]  SBAR
//   ph4: rd {a0(b^1,g0), bX=B(b^1,p0,g0)} st {A1,B0}(kt+2)
//                                                   MFMA a1*bY->acc1  SBAR
template <bool SWIGLU>
__global__ __launch_bounds__(512, 2) void gemm256(
    const bf16_t* __restrict__ A, const bf16_t* __restrict__ B,
    const float* __restrict__ X, float* __restrict__ Outf,
    bf16_t* __restrict__ Outb, int M, int N, int K, int H, int gx) {
  __shared__ char lds[2][2][32768];  // [buf][A=0/B=1][256 rows * 128 B]
  const int t = threadIdx.x;
  const int l = t & 63, w = t >> 6;
  const int wm = w >> 1, wn = w & 1;  // 4M x 2N wave grid
  // bijective XCD swizzle (gridDim.x % 8 == 0 for all our launches)
  const int cpx = (int)gridDim.x >> 3;
  const int bid = (int)blockIdx.x;
  const int wgid = (bid & 7) * cpx + (bid >> 3);
  const int bx = wgid % gx, by = wgid / gx;
  const int m0 = by * 256;
  const int NT = K >> 6;  // K-tiles of 64 (requires NT >= 3)
  const size_t sB = (size_t)K * 2;  // global row stride, bytes
  const int nb = bx * (SWIGLU ? 128 : 256);
  const char* Ab = (const char*)A + (size_t)m0 * sB;
  const char* Bb0 = (const char*)B + (size_t)nb * sB;
  const char* Bb1 = (const char*)B + (size_t)(SWIGLU ? (H + nb) : (nb + 128)) * sB;
  // staging lane constants: lane covers (row = chunk*8 + l>>3, logical gran
  // cg = (l&7) ^ (l>>3)) so linear LDS slot holds the swizzled layout
  const int srow = l >> 3;
  const size_t laneoff = (size_t)srow * sB + (size_t)(((l & 7) ^ srow) << 4);
  const size_t F = (size_t)(w << 4) * sB + laneoff;  // wave w: rows w*16..
  const size_t s8 = 8 * sB;
  // running per-lane global source pointers (column offset kt*128 added per use)
  const char* rA0 = Ab + F;
  const char* rA1 = Ab + (size_t)128 * sB + F;
  const char* rB0 = Bb0 + F;
  const char* rB1 = Bb1 + F;
  // frag-read lane constants
  const int fr_row = (l & 15) << 7;
  const int gk0 = (((l >> 4) ^ (l & 7)) << 4);
  const int gk1 = ((((l >> 4) + 4) ^ (l & 7)) << 4);
  const int wmoff = (wm << 13) + fr_row;  // wm*64 rows * 128 B
  const int wnoff = (wn << 13) + fr_row;
  f32x4 acc[2][4][4] = {};
  bf16x8 a0[4], a1[4], bX[4], bY[4];

  auto ST = [&](const char* s, char* d) {
    async_cp16(s, d);
    async_cp16(s + s8, d + 1024);
  };
  auto RD = [&](bf16x8 (&dst)[4], const char* base, int g) {
#pragma unroll
    for (int j = 0; j < 4; ++j) dst[j] = *(const bf16x8*)(base + j * 2048 + g);
  };
  auto MM = [&](f32x4 (&C)[4][4], bf16x8 (&Af)[4], bf16x8 (&Bfr)[4]) {
#pragma unroll
    for (int i = 0; i < 4; ++i)
#pragma unroll
      for (int j = 0; j < 4; ++j)
        C[i][j] = __builtin_amdgcn_mfma_f32_16x16x32_bf16(Af[i], Bfr[j], C[i][j], 0, 0, 0);
  };

  // ---- prologue: stage kt=0 fully + {A0,A1,B0} of kt=1; pre-read ph1(0) ops
  {
    char* dA0 = lds[0][0] + (w << 11);
    char* dB0 = lds[0][1] + (w << 11);
    char* dA1 = lds[1][0] + (w << 11);
    char* dB1 = lds[1][1] + (w << 11);
    ST(rA0, dA0); ST(rA1, dA0 + 16384);
    ST(rB0, dB0); ST(rB1, dB0 + 16384);
    ST(rA0 + 128, dA1); ST(rA1 + 128, dA1 + 16384);
    ST(rB0 + 128, dB1);
    WAITV(8);  // {A0,A1,B0}(0) landed; B1(0) + {A0,A1,B0}(1) in flight
    SBAR();
    SCHED0();
    RD(a0, lds[0][0] + wmoff, gk0);
    RD(bX, lds[0][1] + wnoff, gk0);
  }

  for (int kt = 0; kt < NT; ++kt) {
    const int b = kt & 1;
    const char* Abl = lds[b][0] + wmoff;
    const char* Bbl = lds[b][1] + wnoff;
    char* dAc = lds[b][0] + (w << 11);          // current-buf stage dests
    char* dBc = lds[b][1] + (w << 11);
    char* dBn = lds[b ^ 1][1] + (w << 11);      // next-buf B dest
    const size_t ko = (size_t)kt * 128;

    // ---------------- phase 1 ----------------
    RD(a1, Abl, gk1);
    RD(bY, Bbl, gk1);
    if (kt + 1 < NT) ST(rB1 + ko + 128, dBn + 16384);
    SCHED0();
    __builtin_amdgcn_s_setprio(1);
    MM(acc[0], a0, bX);
    __builtin_amdgcn_s_setprio(0);
    SCHED0();
    if (kt + 1 < NT) { WAITV(8); } else { WAITV(0); }  // land B1(kt) for ph2
    SBAR();
    SCHED0();

    // ---------------- phase 2 ----------------
    RD(bX, Bbl + 16384, gk0);
    SCHED0();
    __builtin_amdgcn_s_setprio(1);
    MM(acc[0], a1, bY);
    __builtin_amdgcn_s_setprio(0);
    SCHED0();
    SBAR();
    SCHED0();

    // ---------------- phase 3 ----------------
    RD(bY, Bbl + 16384, gk1);
    if (kt + 2 < NT) ST(rA0 + ko + 256, dAc);
    SCHED0();
    __builtin_amdgcn_s_setprio(1);
    MM(acc[1], a0, bX);
    __builtin_amdgcn_s_setprio(0);
    SCHED0();
    if (kt + 2 < NT) { WAITV(4); } else { WAITV(0); }  // land {A0,A1,B0}(kt+1)
    SBAR();
    SCHED0();

    // ---------------- phase 4 ----------------
    if (kt + 1 < NT) {
      RD(a0, lds[b ^ 1][0] + wmoff, gk0);
      RD(bX, lds[b ^ 1][1] + wnoff, gk0);
    }
    if (kt + 2 < NT) {
      ST(rA1 + ko + 256, dAc + 16384);
      ST(rB0 + ko + 256, dBc);
    }
    SCHED0();
    __builtin_amdgcn_s_setprio(1);
    MM(acc[1], a1, bY);
    __builtin_amdgcn_s_setprio(0);
    SCHED0();
    SBAR();
    SCHED0();
  }

  // ---- epilogue ----
  const int col_l = l & 15, row_q = (l >> 4) * 4;
  if (SWIGLU) {
    const int ucol0 = nb + (wn << 6);
#pragma unroll
    for (int i = 0; i < 4; ++i)
#pragma unroll
      for (int j = 0; j < 4; ++j) {
        const int col = ucol0 + j * 16 + col_l;
        const int row = m0 + (wm << 6) + i * 16 + row_q;
#pragma unroll
        for (int r = 0; r < 4; ++r) {
          float hh = acc[0][i][j][r];
          float g = acc[1][i][j][r];
          float s = g / (1.0f + expf(-g));
          Outb[(size_t)(row + r) * N + col] = (bf16_t)(s * hh);
        }
      }
  } else {
#pragma unroll
    for (int p = 0; p < 2; ++p)
#pragma unroll
      for (int i = 0; i < 4; ++i)
#pragma unroll
        for (int j = 0; j < 4; ++j) {
          const int col = nb + p * 128 + (wn << 6) + j * 16 + col_l;
          const int row = m0 + (wm << 6) + i * 16 + row_q;
#pragma unroll
          for (int r = 0; r < 4; ++r) {
            size_t idx = (size_t)(row + r) * N + col;
            Outf[idx] = X[idx] + acc[p][i][j][r];
          }
        }
  }
}

// ---------------- scan pass 1: per-chunk local scan, in-place on Z (d_out) ----------------
__global__ __launch_bounds__(256) void scan1(
    float* __restrict__ Z, const float* __restrict__ P,
    const float* __restrict__ Aarr, const float* __restrict__ Bf, int d) {
  int c = blockIdx.x;
  int col = blockIdx.y * 512 + threadIdx.x * 2;
  __shared__ float sa[64], sp[64], sb[64];
  if (threadIdx.x < 64) {
    int tt = c * 64 + threadIdx.x;
    sa[threadIdx.x] = Aarr[tt];
    sp[threadIdx.x] = P[tt];
    sb[threadIdx.x] = Bf[tt];
  }
  __syncthreads();
  float hx = 0.0f, hy = 0.0f;
  for (int i = 0; i < 64; ++i) {
    int row = c * 64 + i;
    float a = sa[i];
    float2* zp = (float2*)(Z + (size_t)row * d + col);
    if (sb[i] > 0.5f) {
      float2 zv = *zp;
      float pp = sp[i];
      hx = a * hx + pp * zv.x;
      hy = a * hy + pp * zv.y;
    } else {
      hx = a * hx;
      hy = a * hy;
    }
    float2 hv; hv.x = hx; hv.y = hy;
    *zp = hv;
  }
}

// ---------------- scan pass 2: chunk-level carry scan ----------------
__global__ __launch_bounds__(256) void scan2(
    const float* __restrict__ Z, const float* __restrict__ Ac,
    float* __restrict__ Hprev, int d, int NC) {
  int col = blockIdx.x * 256 + threadIdx.x;
  float H = 0.0f;
  for (int c = 0; c < NC; ++c) {
    Hprev[(size_t)c * d + col] = H;
    float E = Z[(size_t)(c * 64 + 63) * d + col];
    H = Ac[c] * H + E;
  }
}

// ---------------- scan pass 3: add carry * intra-chunk prefix ----------------
__global__ __launch_bounds__(256) void scan3(
    float* __restrict__ Z, const float* __restrict__ Pfx,
    const float* __restrict__ Hprev, int d) {
  int row = blockIdx.x;
  int c = row >> 6;
  float pf = Pfx[row];
  int col = threadIdx.x * 8;
  const float* hp = Hprev + (size_t)c * d + col;
  float4 h0 = *(const float4*)hp;
  float4 h1 = *(const float4*)(hp + 4);
  float* zp = Z + (size_t)row * d + col;
  float4 z0 = *(const float4*)zp;
  float4 z1 = *(const float4*)(zp + 4);
  z0.x += pf * h0.x; z0.y += pf * h0.y; z0.z += pf * h0.z; z0.w += pf * h0.w;
  z1.x += pf * h1.x; z1.y += pf * h1.y; z1.z += pf * h1.z; z1.w += pf * h1.w;
  *(float4*)zp = z0;
  *(float4*)(zp + 4) = z1;
}

// ---------------- host ----------------
extern "C" void kernel_launch(void* const* d_in, const int* in_sizes, int n_in,
                              void* d_out, int out_size, void* d_ws, size_t ws_size,
                              hipStream_t stream) {
  const float* x   = (const float*)d_in[0];
  const float* Wq  = (const float*)d_in[1];
  const float* Wk  = (const float*)d_in[2];
  const float* fc1 = (const float*)d_in[3];
  const float* fc2 = (const float*)d_in[4];
  const float* nw  = (const float*)d_in[5];
  const int*   cu  = (const int*)d_in[6];
  const int ncu = in_sizes[6];
  const int d = in_sizes[5];            // 2048
  const int T = in_sizes[0] / d;        // 8192
  const int h = in_sizes[4] / d;        // 8192
  const int NC = T / 64;                // 128 chunks
  float* zout = (float*)d_out;

  char* ws = (char*)d_ws;
  size_t off = 0;
  auto alloc = [&](size_t bytes) -> void* {
    void* p = ws + off;
    off += (bytes + 255) & ~(size_t)255;
    return p;
  };
  // qk [T, 2d] fp32; later reused as u [T, h] bf16 (same byte size)
  float*  qk   = (float*)alloc((size_t)T * 2 * d * 4);
  bf16_t* u    = (bf16_t*)qk;
  bf16_t* xn   = (bf16_t*)alloc((size_t)T * d * 2);
  // region A: first {Xh, Xl, Wth, Wtl} (fp16 splits), later {fc1t, fc2t} (bf16)
  size_t szXh = (size_t)T * d * 2;          // 33.5 MB
  size_t szWt = (size_t)2 * d * d * 2;      // 16.8 MB
  char* regionA = (char*)alloc(2 * szXh + 2 * szWt);
  f16_t* Xh  = (f16_t*)regionA;
  f16_t* Xl  = (f16_t*)(regionA + szXh);
  f16_t* Wth = (f16_t*)(regionA + 2 * szXh);
  f16_t* Wtl = (f16_t*)(regionA + 2 * szXh + szWt);
  bf16_t* fc1t = (bf16_t*)regionA;                           // [2h, d]
  bf16_t* fc2t = (bf16_t*)(regionA + (size_t)2 * h * d * 2); // [d, h]
  float*  P    = (float*)alloc((size_t)T * 4);
  float*  Aa   = (float*)alloc((size_t)T * 4);
  float*  Bf   = (float*)alloc((size_t)T * 4);
  float*  Pfx  = (float*)alloc((size_t)T * 4);
  float*  Ac   = (float*)alloc((size_t)NC * 4);
  float*  Hprev= (float*)alloc((size_t)NC * d * 4);

  // ---- routing: q/k projections on matrix cores via fp16 split ----
  split_x<<<dim3(T * d / 1024), 256, 0, stream>>>(x, Xh, Xl, T * d / 4);
  transpose_split<<<dim3(d / 32, d / 32), 256, 0, stream>>>(Wq, Wth, Wtl, d, d);
  transpose_split<<<dim3(d / 32, d / 32), 256, 0, stream>>>(
      Wk, Wth + (size_t)d * d, Wtl + (size_t)d * d, d, d);
  gemm_f16_split<<<dim3(2 * d / 128, T / 128), 256, 0, stream>>>(
      Xh, Xl, Wth, Wtl, qk, T, 2 * d, d, 1.0f / WSCALE);
  cos_p<<<dim3(T), 256, 0, stream>>>(qk, cu, ncu, P, Aa, Bf, d);
  pfx_kernel<<<dim3(1), 128, 0, stream>>>(Aa, Pfx, Ac, T);

  // ---- MLP weights into region A (splits dead now) ----
  transpose_cast<<<dim3(2 * h / 32, d / 32), 256, 0, stream>>>(fc1, fc1t, d, 2 * h);
  transpose_cast<<<dim3(d / 32, h / 32), 256, 0, stream>>>(fc2, fc2t, h, d);
  rmsnorm_cast<<<dim3(T), 256, 0, stream>>>(x, nw, xn, d);
  // u reuses qk space (qk dead after cos_p)
  gemm256<true><<<dim3((h / 128) * (T / 256)), 512, 0, stream>>>(
      xn, fc1t, nullptr, nullptr, u, T, h, d, h, h / 128);
  gemm256<false><<<dim3((d / 256) * (T / 256)), 512, 0, stream>>>(
      u, fc2t, x, zout, nullptr, T, d, h, 0, d / 256);
  // ---- EMA scan (3 passes, in place on d_out) ----
  scan1<<<dim3(NC, d / 512), 256, 0, stream>>>(zout, P, Aa, Bf, d);
  scan2<<<dim3(d / 256), 256, 0, stream>>>(zout, Ac, Hprev, d, NC);
  scan3<<<dim3(T), 256, 0, stream>>>(zout, Pfx, Hprev, d);
}